// Round 2
// baseline (228.548 us; speedup 1.0000x reference)
//
#include <hip/hip_runtime.h>

// GCN layer, B=8 N=512 ND=64 ED=16 OD=64, all fp32.
// Identity used: sum_j adj_ij * (edge_feat_ij @ We^T + We_b)
//              = (sum_j adj_ij * edge_feat_ij) @ We^T + deg_i * We_b
// => only the masked edge_feat reduction touches the big tensors.

#define BB 8
#define NN 512
#define ND 64
#define ED 16
#define OD 64

__global__ __launch_bounds__(256) void gcn_fused_kernel(
    const float* __restrict__ h,     // (B,N,ND)
    const int*   __restrict__ adj,   // (B,N,N)
    const float* __restrict__ ef,    // (B,N,N,ED)
    const float* __restrict__ Wn_w,  // (OD,ND)
    const float* __restrict__ Wn_b,  // (OD)
    const float* __restrict__ We_w,  // (OD,ED)
    const float* __restrict__ We_b,  // (OD)
    const float* __restrict__ Ws_w,  // (OD,ND)
    const float* __restrict__ Ws_b,  // (OD)
    float* __restrict__ out)         // (B,N,OD)
{
    const int row = blockIdx.x;      // b*N + i  (0..4095)
    const int t   = threadIdx.x;     // 0..255
    const int q   = t & 3;           // which float4 quad of the ED=16 channels
    const int jg  = t >> 2;          // 0..63 j-group

    __shared__ float4 esum_s[256];   // [jg*4 + q]
    __shared__ float  deg_s[64];
    __shared__ float  hs[ND];

    // stage h row into LDS (reused by 64 epilogue threads)
    if (t < ND) hs[t] = h[(size_t)row * ND + t];

    const float4* efrow  = (const float4*)(ef + (size_t)row * NN * ED);
    const int*    adjrow = adj + (size_t)row * NN;

    // Phase 1: masked reduction over j.  Lane layout: 64 lanes = 16 j's x 4
    // quads -> each float4 load instruction covers 1 KiB contiguous.
    float4 acc = make_float4(0.f, 0.f, 0.f, 0.f);
    float  dacc = 0.f;
    #pragma unroll
    for (int k = 0; k < NN / 64; ++k) {
        const int j = jg + k * 64;
        const float  a = (float)adjrow[j];
        const float4 v = efrow[j * 4 + q];
        acc.x += a * v.x;
        acc.y += a * v.y;
        acc.z += a * v.z;
        acc.w += a * v.w;
        dacc  += a;
    }
    esum_s[jg * 4 + q] = acc;
    if (q == 0) deg_s[jg] = dacc;
    __syncthreads();

    // tree-reduce over the 64 j-groups
    #pragma unroll
    for (int s = 32; s > 0; s >>= 1) {
        if (jg < s) {
            float4 m = esum_s[jg * 4 + q];
            float4 o4 = esum_s[(jg + s) * 4 + q];
            m.x += o4.x; m.y += o4.y; m.z += o4.z; m.w += o4.w;
            esum_s[jg * 4 + q] = m;
            if (q == 0) deg_s[jg] += deg_s[jg + s];
        }
        __syncthreads();
    }

    // Phase 2: 64 threads, one output channel each.
    if (t < OD) {
        const int o = t;
        const float deg = deg_s[0];
        const float* __restrict__ es = (const float*)esum_s; // channels 0..15

        float nm = Wn_b[o];
        float sm = Ws_b[o];
        const float* wn = Wn_w + o * ND;
        const float* ws = Ws_w + o * ND;
        #pragma unroll
        for (int k = 0; k < ND; ++k) {
            const float hk = hs[k];
            nm = fmaf(hk, wn[k], nm);
            sm = fmaf(hk, ws[k], sm);
        }

        float em = deg * We_b[o];
        const float* we = We_w + o * ED;
        #pragma unroll
        for (int e = 0; e < ED; ++e) em = fmaf(es[e], we[e], em);

        const float degc = fmaxf(deg, 1.0f);
        const float agg  = (nm * deg + em) / degc;
        const float r    = agg + sm;
        out[(size_t)row * OD + o] = fmaxf(r, 0.0f);
    }
}

extern "C" void kernel_launch(void* const* d_in, const int* in_sizes, int n_in,
                              void* d_out, int out_size, void* d_ws, size_t ws_size,
                              hipStream_t stream) {
    const float* h    = (const float*)d_in[0];
    const int*   adj  = (const int*)  d_in[1];
    const float* ef   = (const float*)d_in[2];
    const float* Wn_w = (const float*)d_in[3];
    const float* Wn_b = (const float*)d_in[4];
    const float* We_w = (const float*)d_in[5];
    const float* We_b = (const float*)d_in[6];
    const float* Ws_w = (const float*)d_in[7];
    const float* Ws_b = (const float*)d_in[8];
    float* out = (float*)d_out;

    dim3 grid(BB * NN);   // 4096 blocks, one per (b,i) row
    dim3 block(256);
    gcn_fused_kernel<<<grid, block, 0, stream>>>(
        h, adj, ef, Wn_w, Wn_b, We_w, We_b, Ws_w, Ws_b, out);
}

// Round 3
// 220.410 us; speedup vs baseline: 1.0369x; 1.0369x over previous
//
#include <hip/hip_runtime.h>

// GCN layer, B=8 N=512 ND=64 ED=16 OD=64, all fp32.
// Identity: sum_j adj_ij * (ef_ij @ We^T + We_b)
//         = (sum_j adj_ij * ef_ij) @ We^T + deg_i * We_b
// => one masked pass over ef/adj; tiny GEMVs in the epilogue.
// R2 change: adj staged in LDS (coalesced int2), ef load PREDICATED on
// adj!=0 so masked lanes fetch nothing (~50% of ef lines skipped).

#define BB 8
#define NN 512
#define ND 64
#define ED 16
#define OD 64

__global__ __launch_bounds__(256) void gcn_fused_kernel(
    const float* __restrict__ h,     // (B,N,ND)
    const int*   __restrict__ adj,   // (B,N,N)
    const float* __restrict__ ef,    // (B,N,N,ED)
    const float* __restrict__ Wn_w,  // (OD,ND)
    const float* __restrict__ Wn_b,  // (OD)
    const float* __restrict__ We_w,  // (OD,ED)
    const float* __restrict__ We_b,  // (OD)
    const float* __restrict__ Ws_w,  // (OD,ND)
    const float* __restrict__ Ws_b,  // (OD)
    float* __restrict__ out)         // (B,N,OD)
{
    const int row = blockIdx.x;      // b*N + i  (0..4095)
    const int t   = threadIdx.x;     // 0..255
    const int q   = t & 3;           // float4 quad of the ED=16 channels
    const int jg  = t >> 2;          // 0..63 j-group

    __shared__ int    adj_s[NN];
    __shared__ float4 esum_s[256];   // [jg*4 + q]
    __shared__ float  deg_s[64];
    __shared__ float  hs[ND];

    const int* adjrow = adj + (size_t)row * NN;
    // coalesced adj stage: 256 threads x int2 = 512 ints
    ((int2*)adj_s)[t] = ((const int2*)adjrow)[t];
    if (t < ND) hs[t] = h[(size_t)row * ND + t];
    __syncthreads();

    const float4* efrow = (const float4*)(ef + (size_t)row * NN * ED);

    // Phase 1: masked reduction over j. 64 lanes = 16 j's x 4 quads;
    // a fully-dense j-window is 1 KiB contiguous per load instruction.
    // Lanes whose adj==0 skip the load entirely (no HBM fetch).
    float4 acc = make_float4(0.f, 0.f, 0.f, 0.f);
    float  dacc = 0.f;
    #pragma unroll
    for (int k = 0; k < NN / 64; ++k) {
        const int j = jg + k * 64;
        const int a = adj_s[j];
        dacc += (float)a;
        if (a != 0) {
            const float  af = (float)a;
            const float4 v  = efrow[j * 4 + q];
            acc.x += af * v.x;
            acc.y += af * v.y;
            acc.z += af * v.z;
            acc.w += af * v.w;
        }
    }
    esum_s[jg * 4 + q] = acc;
    if (q == 0) deg_s[jg] = dacc;
    __syncthreads();

    // tree-reduce over the 64 j-groups
    #pragma unroll
    for (int s = 32; s > 0; s >>= 1) {
        if (jg < s) {
            float4 m  = esum_s[jg * 4 + q];
            float4 o4 = esum_s[(jg + s) * 4 + q];
            m.x += o4.x; m.y += o4.y; m.z += o4.z; m.w += o4.w;
            esum_s[jg * 4 + q] = m;
            if (q == 0) deg_s[jg] += deg_s[jg + s];
        }
        __syncthreads();
    }

    // Phase 2: 64 threads, one output channel each.
    if (t < OD) {
        const int o = t;
        const float deg = deg_s[0];
        const float* __restrict__ es = (const float*)esum_s; // channels 0..15

        float nm = Wn_b[o];
        float sm = Ws_b[o];
        const float* wn = Wn_w + o * ND;
        const float* ws = Ws_w + o * ND;
        #pragma unroll
        for (int k = 0; k < ND; ++k) {
            const float hk = hs[k];
            nm = fmaf(hk, wn[k], nm);
            sm = fmaf(hk, ws[k], sm);
        }

        float em = deg * We_b[o];
        const float* we = We_w + o * ED;
        #pragma unroll
        for (int e = 0; e < ED; ++e) em = fmaf(es[e], we[e], em);

        const float degc = fmaxf(deg, 1.0f);
        const float agg  = (nm * deg + em) / degc;
        const float r    = agg + sm;
        out[(size_t)row * OD + o] = fmaxf(r, 0.0f);
    }
}

extern "C" void kernel_launch(void* const* d_in, const int* in_sizes, int n_in,
                              void* d_out, int out_size, void* d_ws, size_t ws_size,
                              hipStream_t stream) {
    const float* h    = (const float*)d_in[0];
    const int*   adj  = (const int*)  d_in[1];
    const float* ef   = (const float*)d_in[2];
    const float* Wn_w = (const float*)d_in[3];
    const float* Wn_b = (const float*)d_in[4];
    const float* We_w = (const float*)d_in[5];
    const float* We_b = (const float*)d_in[6];
    const float* Ws_w = (const float*)d_in[7];
    const float* Ws_b = (const float*)d_in[8];
    float* out = (float*)d_out;

    dim3 grid(BB * NN);   // 4096 blocks, one per (b,i) row
    dim3 block(256);
    gcn_fused_kernel<<<grid, block, 0, stream>>>(
        h, adj, ef, Wn_w, Wn_b, We_w, We_b, Ws_w, Ws_b, out);
}